// Round 5
// baseline (563.625 us; speedup 1.0000x reference)
//
#include <hip/hip_runtime.h>
#include <hip/hip_bf16.h>

typedef unsigned short u16;
typedef __attribute__((ext_vector_type(8))) __bf16 bf16x8;
typedef __attribute__((ext_vector_type(4))) float f32x4;
typedef __attribute__((ext_vector_type(4))) short s16x4;

// ---------- helpers ----------
__device__ __forceinline__ u16 f2b(float f) {            // f32 -> bf16 RNE (manual)
  unsigned u = __builtin_bit_cast(unsigned, f);
  u = (u + 0x7fffu + ((u >> 16) & 1u)) >> 16;
  return (u16)u;
}

__device__ __forceinline__ u16 f2b_fast(float f) {       // native: enables v_cvt_pk_bf16_f32
  return __builtin_bit_cast(u16, (__bf16)f);
}

__device__ __forceinline__ unsigned pack2(float a, float b) {  // 2 f32 -> packed bf16x2
  return (unsigned)f2b_fast(a) | ((unsigned)f2b_fast(b) << 16);
}

__device__ __forceinline__ f32x4 mfma_bf16(uint4 a, uint4 b, f32x4 c) {
  return __builtin_amdgcn_mfma_f32_16x16x32_bf16(
      __builtin_bit_cast(bf16x8, a), __builtin_bit_cast(bf16x8, b), c, 0, 0, 0);
}

// 16x16x16 bf16 MFMA: A/B = 2 VGPRs (4 bf16), C/D = 4 f32. B-frag k=(lane>>4)*4+e.
__device__ __forceinline__ f32x4 mfma_bf16_k16(uint2 a, uint2 b, f32x4 c) {
#if __has_builtin(__builtin_amdgcn_mfma_f32_16x16x16bf16_1k)
  return __builtin_amdgcn_mfma_f32_16x16x16bf16_1k(
      __builtin_bit_cast(s16x4, a), __builtin_bit_cast(s16x4, b), c, 0, 0, 0);
#elif __has_builtin(__builtin_amdgcn_mfma_f32_16x16x16_bf16)
  return __builtin_amdgcn_mfma_f32_16x16x16_bf16(
      __builtin_bit_cast(s16x4, a), __builtin_bit_cast(s16x4, b), c, 0, 0, 0);
#else
  f32x4 d;
  asm volatile("v_mfma_f32_16x16x16_bf16 %0, %1, %2, %3"
               : "=v"(d) : "v"(a), "v"(b), "v"(c));
  return d;
#endif
}

__device__ __forceinline__ void gload_lds16(const u16* g, u16* l) {
  __builtin_amdgcn_global_load_lds(
      (const __attribute__((address_space(1))) unsigned int*)(g),
      (__attribute__((address_space(3))) unsigned int*)(l), 16, 0, 0);
}

__device__ __forceinline__ void cast8(const float* __restrict__ s, u16* __restrict__ d) {
  float4 a = *(const float4*)s;
  float4 b = *(const float4*)(s + 4);
  ushort4 lo, hi;
  lo.x = f2b(a.x); lo.y = f2b(a.y); lo.z = f2b(a.z); lo.w = f2b(a.w);
  hi.x = f2b(b.x); hi.y = f2b(b.y); hi.z = f2b(b.z); hi.w = f2b(b.w);
  *(ushort4*)d = lo;
  *(ushort4*)(d + 4) = hi;
}

// ---------- cast kernels ----------
__global__ __launch_bounds__(256) void cast_x(const float* __restrict__ src,
                                              u16* __restrict__ dst, int n) {
  int i = (blockIdx.x * 256 + threadIdx.x) * 8;
  if (i + 8 <= n) cast8(src + i, dst + i);
}

__global__ __launch_bounds__(256) void cast_w4(const float* __restrict__ w0,
                                               const float* __restrict__ w1,
                                               const float* __restrict__ w2,
                                               const float* __restrict__ w3,
                                               u16* __restrict__ dst) {
  const float* s = (blockIdx.y == 0) ? w0 : (blockIdx.y == 1) ? w1
                 : (blockIdx.y == 2) ? w2 : w3;
  u16* d = dst + (size_t)blockIdx.y * (1u << 20);
  int i = (blockIdx.x * 256 + threadIdx.x) * 8;
  cast8(s + i, d + i);
}

// mask -> additive bias {0, -3e38}
__global__ __launch_bounds__(256) void mask_bias(const int* __restrict__ msk,
                                                 float* __restrict__ mb, int n) {
  int i = blockIdx.x * 256 + threadIdx.x;
  if (i < n) mb[i] = msk[i] ? 0.0f : -3.0e38f;
}

// ---------- fused QKV GEMM: 128x128 tiles, grid (24, 64) ----------
// blockIdx.x: [0,8)=Q, [8,16)=K, [16,24)=V (stored transposed to Vt[b][h][hd][S]).
__global__ __launch_bounds__(256) void gemm_qkv(const u16* __restrict__ A,
                                                const u16* __restrict__ W,
                                                const float* __restrict__ bqp,
                                                const float* __restrict__ bkp,
                                                const float* __restrict__ bvp,
                                                u16* __restrict__ Qb,
                                                u16* __restrict__ Kb,
                                                u16* __restrict__ Vt) {
  constexpr int N = 1024, K = 1024;
  __shared__ u16 lA[128 * 32];
  __shared__ u16 lB[128 * 32];
  const int which = blockIdx.x >> 3;
  const int bx = blockIdx.x & 7;
  const u16* Bm = W + ((size_t)which << 20);
  const float* bias = (which == 0) ? bqp : (which == 1) ? bkp : bvp;

  const int tid = threadIdx.x;
  const int lane = tid & 63;
  const int w = tid >> 6;
  const int wr = w >> 1, wc = w & 1;
  const int rowBase = blockIdx.y * 128, colBase = bx * 128;
  const int lo = lane & 15, g = lane >> 4;

  f32x4 acc[4][4] = {};

  const int r0 = tid >> 2;
  const int c0 = (tid & 3) * 8;
  const u16* gA = A + (size_t)(rowBase + r0) * K + c0;
  const u16* gB = Bm + (size_t)(colBase + r0) * K + c0;
  u16* lAd = lA + w * 512;
  u16* lBd = lB + w * 512;

#pragma unroll 1
  for (int k0 = 0; k0 < K; k0 += 32) {
    gload_lds16(gA + k0, lAd);
    gload_lds16(gA + k0 + 64 * K, lAd + 2048);
    gload_lds16(gB + k0, lBd);
    gload_lds16(gB + k0 + 64 * K, lBd + 2048);
    __syncthreads();
    uint4 af[4], bf[4];
#pragma unroll
    for (int m = 0; m < 4; ++m)
      af[m] = *(const uint4*)&lA[(wr * 64 + m * 16 + lo) * 32 + g * 8];
#pragma unroll
    for (int n = 0; n < 4; ++n)
      bf[n] = *(const uint4*)&lB[(wc * 64 + n * 16 + lo) * 32 + g * 8];
#pragma unroll
    for (int m = 0; m < 4; ++m)
#pragma unroll
      for (int n = 0; n < 4; ++n)
        acc[m][n] = mfma_bf16(af[m], bf[n], acc[m][n]);
    __syncthreads();
  }

  const int cr = g * 4;
  if (which == 2) {  // V: transposed store
#pragma unroll
    for (int m = 0; m < 4; ++m)
#pragma unroll
      for (int n = 0; n < 4; ++n) {
        int i0 = rowBase + wr * 64 + m * 16 + cr;
        int jf = colBase + wc * 64 + n * 16 + lo;
        float bv = bias[jf];
        int bb = i0 >> 11, s0 = i0 & 2047;
        int hh = jf >> 6, dd = jf & 63;
        ushort4 pk;
        pk.x = f2b(acc[m][n][0] + bv);
        pk.y = f2b(acc[m][n][1] + bv);
        pk.z = f2b(acc[m][n][2] + bv);
        pk.w = f2b(acc[m][n][3] + bv);
        *(ushort4*)(Vt + ((size_t)((bb * 16 + hh) * 64 + dd)) * 2048 + s0) = pk;
      }
  } else {
    u16* dst = which ? Kb : Qb;
#pragma unroll
    for (int m = 0; m < 4; ++m)
#pragma unroll
      for (int n = 0; n < 4; ++n) {
        int gr = rowBase + wr * 64 + m * 16 + cr;
        int gc = colBase + wc * 64 + n * 16 + lo;
        float bv = bias[gc];
#pragma unroll
        for (int j = 0; j < 4; ++j)
          dst[(size_t)(gr + j) * N + gc] = f2b(acc[m][n][j] + bv);
      }
  }
}

// ---------- O-projection GEMM (f32 out) ----------
__global__ __launch_bounds__(256) void gemm_out(const u16* __restrict__ A,
                                                const u16* __restrict__ Bm,
                                                const float* __restrict__ bias,
                                                float* __restrict__ Cout) {
  constexpr int N = 1024, K = 1024;
  __shared__ u16 lA[128 * 32];
  __shared__ u16 lB[128 * 32];
  const int tid = threadIdx.x;
  const int lane = tid & 63;
  const int w = tid >> 6;
  const int wr = w >> 1, wc = w & 1;
  const int rowBase = blockIdx.y * 128, colBase = blockIdx.x * 128;
  const int lo = lane & 15, g = lane >> 4;

  f32x4 acc[4][4] = {};
  const int r0 = tid >> 2;
  const int c0 = (tid & 3) * 8;
  const u16* gA = A + (size_t)(rowBase + r0) * K + c0;
  const u16* gB = Bm + (size_t)(colBase + r0) * K + c0;
  u16* lAd = lA + w * 512;
  u16* lBd = lB + w * 512;

#pragma unroll 1
  for (int k0 = 0; k0 < K; k0 += 32) {
    gload_lds16(gA + k0, lAd);
    gload_lds16(gA + k0 + 64 * K, lAd + 2048);
    gload_lds16(gB + k0, lBd);
    gload_lds16(gB + k0 + 64 * K, lBd + 2048);
    __syncthreads();
    uint4 af[4], bf[4];
#pragma unroll
    for (int m = 0; m < 4; ++m)
      af[m] = *(const uint4*)&lA[(wr * 64 + m * 16 + lo) * 32 + g * 8];
#pragma unroll
    for (int n = 0; n < 4; ++n)
      bf[n] = *(const uint4*)&lB[(wc * 64 + n * 16 + lo) * 32 + g * 8];
#pragma unroll
    for (int m = 0; m < 4; ++m)
#pragma unroll
      for (int n = 0; n < 4; ++n)
        acc[m][n] = mfma_bf16(af[m], bf[n], acc[m][n]);
    __syncthreads();
  }

  const int cr = g * 4;
#pragma unroll
  for (int m = 0; m < 4; ++m)
#pragma unroll
    for (int n = 0; n < 4; ++n) {
      int gr = rowBase + wr * 64 + m * 16 + cr;
      int gc = colBase + wc * 64 + n * 16 + lo;
      float bv = bias[gc];
#pragma unroll
      for (int j = 0; j < 4; ++j)
        Cout[(size_t)(gr + j) * N + gc] = acc[m][n][j] + bv;
    }
}

// ---------- flash attention with ALiBi: swapped QK^T + lane-local PV ----------
// 4 independent waves/block; wave owns 32 q, KVBLK=128.
// QK^T as mfma(K,Q): C row = k-local (4g+j), col = q-local (lo).
// Softmax reduce = in-lane tree + xor16/xor32 shuffles (2 per m).
// PV via 16x16x16 mfma: its B-frag layout (k=4g+e) EXACTLY matches the
// per-lane P layout -> no cross-lane movement, no LDS for P.
__global__ __launch_bounds__(256) void attn_fa(const u16* __restrict__ Qb,
                                               const u16* __restrict__ Kb,
                                               const u16* __restrict__ Vt,
                                               const float* __restrict__ mb,
                                               u16* __restrict__ Ob) {
  constexpr int S = 2048, D = 1024, H = 16;
  __shared__ float kbs[S];    // per-(b,h) combined ALiBi+mask bias, log2 domain
  const int tid = threadIdx.x, lane = tid & 63, w = tid >> 6;
  const int lo = lane & 15, g = lane >> 4;
  const int b = blockIdx.z, h = blockIdx.y;
  const int qt = blockIdx.x * 128 + w * 32;
  const float LOG2E = 1.4426950408889634f;
  const float slope2 = exp2f(-(float)h / 16.0f) * LOG2E;  // slope * log2(e)
  const float c1 = 0.125f * LOG2E;                        // scale * log2(e)

  {  // kbs[s] = slope2*s + maskbias[s]
    const float* mbb = mb + b * S;
    int s0 = tid * 8;
    float4 aa = *(const float4*)(mbb + s0);
    float4 bb = *(const float4*)(mbb + s0 + 4);
    kbs[s0 + 0] = fmaf(slope2, (float)(s0 + 0), aa.x);
    kbs[s0 + 1] = fmaf(slope2, (float)(s0 + 1), aa.y);
    kbs[s0 + 2] = fmaf(slope2, (float)(s0 + 2), aa.z);
    kbs[s0 + 3] = fmaf(slope2, (float)(s0 + 3), aa.w);
    kbs[s0 + 4] = fmaf(slope2, (float)(s0 + 4), bb.x);
    kbs[s0 + 5] = fmaf(slope2, (float)(s0 + 5), bb.y);
    kbs[s0 + 6] = fmaf(slope2, (float)(s0 + 6), bb.z);
    kbs[s0 + 7] = fmaf(slope2, (float)(s0 + 7), bb.w);
  }
  __syncthreads();

  // Q fragments (B-operand for swapped QK^T): lane holds Q[qt+m*16+lo][g*8..]
  uint4 aq[2][2];
#pragma unroll
  for (int m = 0; m < 2; ++m) {
    const u16* qp = Qb + (size_t)(b * S + qt + m * 16 + lo) * D + h * 64 + g * 8;
    aq[m][0] = *(const uint4*)qp;
    aq[m][1] = *(const uint4*)(qp + 32);
  }

  float mrow[2] = {-3.0e38f, -3.0e38f};
  float lrow[2] = {0.0f, 0.0f};
  f32x4 o[2][4] = {};   // o[m][dn]: O^T fragment, row d = dn*16+4g+j, col q = m*16+lo

  const u16* kbase = Kb + (size_t)b * S * D + h * 64;
  const u16* vbase = Vt + (size_t)(b * H + h) * 64 * S;

#pragma unroll 1
  for (int kt = 0; kt < S; kt += 128) {
    // ---- K fragment loads ----
    uint4 kf[8][2];
#pragma unroll
    for (int n = 0; n < 8; ++n) {
      const u16* kr = kbase + (size_t)(kt + n * 16 + lo) * D + g * 8;
      kf[n][0] = *(const uint4*)kr;
      kf[n][1] = *(const uint4*)(kr + 32);
    }
    // ---- swapped QK^T: sc[m][n] row=k-local(4g+j), col=q(lo) ----
    f32x4 sc[2][8];
    __builtin_amdgcn_s_setprio(1);
#pragma unroll
    for (int n = 0; n < 8; ++n)
#pragma unroll
      for (int m = 0; m < 2; ++m) {
        f32x4 z4 = {0.f, 0.f, 0.f, 0.f};
        z4 = mfma_bf16(kf[n][0], aq[m][0], z4);
        sc[m][n] = mfma_bf16(kf[n][1], aq[m][1], z4);
      }
    __builtin_amdgcn_s_setprio(0);
    // ---- bias: z = s*c1 + kbs[k], k = kt+16n+4g+j ----
#pragma unroll
    for (int n = 0; n < 8; ++n) {
      f32x4 kbv = *(const f32x4*)&kbs[kt + n * 16 + g * 4];
#pragma unroll
      for (int m = 0; m < 2; ++m)
#pragma unroll
        for (int j = 0; j < 4; ++j)
          sc[m][n][j] = fmaf(sc[m][n][j], c1, kbv[j]);
    }
    // ---- online softmax per q-column (in-lane tree + 2 shuffles) ----
#pragma unroll
    for (int m = 0; m < 2; ++m) {
      f32x4 vm = sc[m][0];
#pragma unroll
      for (int n = 1; n < 8; ++n)
#pragma unroll
        for (int j = 0; j < 4; ++j) vm[j] = fmaxf(vm[j], sc[m][n][j]);
      float pm = fmaxf(fmaxf(vm[0], vm[1]), fmaxf(vm[2], vm[3]));
      pm = fmaxf(pm, __shfl_xor(pm, 16));
      pm = fmaxf(pm, __shfl_xor(pm, 32));
      float mn = fmaxf(mrow[m], pm);
      float rs = exp2f(mrow[m] - mn);
      mrow[m] = mn;
      f32x4 vs = {0.f, 0.f, 0.f, 0.f};
#pragma unroll
      for (int n = 0; n < 8; ++n)
#pragma unroll
        for (int j = 0; j < 4; ++j) {
          float p = exp2f(sc[m][n][j] - mn);
          sc[m][n][j] = p;
          vs[j] += p;
        }
      float rsum = (vs[0] + vs[1]) + (vs[2] + vs[3]);
      rsum += __shfl_xor(rsum, 16);
      rsum += __shfl_xor(rsum, 32);
      lrow[m] = lrow[m] * rs + rsum;
#pragma unroll
      for (int dn = 0; dn < 4; ++dn)
#pragma unroll
        for (int j = 0; j < 4; ++j) o[m][dn][j] *= rs;
    }
    // ---- PV via 16x16x16 mfma: pb is lane-local (k=4g+j == B-frag slots) ----
#pragma unroll
    for (int n = 0; n < 8; ++n) {
      uint2 pb[2];
#pragma unroll
      for (int m = 0; m < 2; ++m) {
        pb[m].x = pack2(sc[m][n][0], sc[m][n][1]);
        pb[m].y = pack2(sc[m][n][2], sc[m][n][3]);
      }
      __builtin_amdgcn_s_setprio(1);
#pragma unroll
      for (int dn = 0; dn < 4; ++dn) {
        const u16* vr = vbase + (size_t)(dn * 16 + lo) * S + kt + n * 16 + g * 4;
        uint2 va = *(const uint2*)vr;
        o[0][dn] = mfma_bf16_k16(va, pb[0], o[0][dn]);
        o[1][dn] = mfma_bf16_k16(va, pb[1], o[1][dn]);
      }
      __builtin_amdgcn_s_setprio(0);
    }
  }
  // ---- normalize + store bf16 [B,S,H,hd]; ushort4 per (m,dn) ----
#pragma unroll
  for (int m = 0; m < 2; ++m) {
    float inv = 1.0f / fmaxf(lrow[m], 1e-30f);
    u16* orow = Ob + (size_t)(b * S + qt + m * 16 + lo) * D + h * 64 + g * 4;
#pragma unroll
    for (int dn = 0; dn < 4; ++dn) {
      ushort4 st;
      st.x = f2b_fast(o[m][dn][0] * inv);
      st.y = f2b_fast(o[m][dn][1] * inv);
      st.z = f2b_fast(o[m][dn][2] * inv);
      st.w = f2b_fast(o[m][dn][3] * inv);
      *(ushort4*)(orow + dn * 16) = st;
    }
  }
}

// ---------- host launcher ----------
extern "C" void kernel_launch(void* const* d_in, const int* in_sizes, int n_in,
                              void* d_out, int out_size, void* d_ws, size_t ws_size,
                              hipStream_t stream) {
  (void)in_sizes; (void)n_in; (void)out_size; (void)ws_size;
  const float* x  = (const float*)d_in[0];
  const float* Wq = (const float*)d_in[1];
  const float* bq = (const float*)d_in[2];
  const float* Wk = (const float*)d_in[3];
  const float* bk = (const float*)d_in[4];
  const float* Wv = (const float*)d_in[5];
  const float* bv = (const float*)d_in[6];
  const float* Wo = (const float*)d_in[7];
  const float* bo = (const float*)d_in[8];
  const int*  msk = (const int*)d_in[9];
  float* out = (float*)d_out;

  char* ws = (char*)d_ws;
  u16* xb  = (u16*)(ws);                       // 16MB; reused as attention output
  u16* Qb  = (u16*)(ws + ((size_t)16 << 20));
  u16* Kb  = (u16*)(ws + ((size_t)32 << 20));
  u16* Vt  = (u16*)(ws + ((size_t)48 << 20));
  u16* Wqb = (u16*)(ws + ((size_t)64 << 20));  // 4 weights, 2MB each
  float* mbf = (float*)(ws + ((size_t)72 << 20));  // mask bias, 32KB

  cast_x<<<4096, 256, 0, stream>>>(x, xb, 8192 * 1024);
  cast_w4<<<dim3(512, 4), 256, 0, stream>>>(Wq, Wk, Wv, Wo, Wqb);
  mask_bias<<<32, 256, 0, stream>>>(msk, mbf, 8192);

  gemm_qkv<<<dim3(24, 64), 256, 0, stream>>>(xb, Wqb, bq, bk, bv, Qb, Kb, Vt);

  attn_fa<<<dim3(16, 16, 4), 256, 0, stream>>>(Qb, Kb, Vt, mbf, xb /*Ob reuses xb*/);

  gemm_out<<<dim3(8, 64), 256, 0, stream>>>(xb, Wqb + (3u << 20), bo, out);
}